// Round 8
// baseline (249.114 us; speedup 1.0000x reference)
//
#include <hip/hip_runtime.h>
#include <hip/hip_bf16.h>

#define HH   300
#define NB   128
#define NTT  64
#define NP   8192        // B*T
#define NCH  12
#define KPAD 320         // padded per-operand K (300 -> 320)
#define KCAT 640         // concat K for score GEMM
#define NTI  13          // 208/16 n-tiles
#define K6K  640         // k_out padded K (600 -> 640)

typedef __attribute__((ext_vector_type(8))) short short8;
typedef __attribute__((ext_vector_type(4))) short short4v;
typedef __attribute__((ext_vector_type(4))) float f32x4;

__device__ __forceinline__ float fsig(float x){
  return __builtin_amdgcn_rcpf(1.f + __expf(-x));
}
__device__ __forceinline__ float ftanh(float x){
  float e = __expf(2.f*x);
  return 1.f - 2.f*__builtin_amdgcn_rcpf(e + 1.f);   // safe at +/-inf
}
__device__ __forceinline__ float bf2f(unsigned short u){
  return __uint_as_float(((unsigned)u) << 16);
}
__device__ __forceinline__ unsigned short f2bf(float f){      // RNE (prep only)
  __hip_bfloat16 h = __float2bfloat16(f);
  return *reinterpret_cast<unsigned short*>(&h);
}
__device__ __forceinline__ unsigned short rbf(float f){       // round-half-up, 2 ops
  return (unsigned short)((__float_as_uint(f) + 0x8000u) >> 16);
}
// XOR-swizzled LDS byte offset; strideShorts*2 must be a multiple of 128B
__device__ __forceinline__ int swzb(int row, int col, int strideShorts){
  int byte = row*(strideShorts*2) + (col<<1);
  return byte ^ ((row & 7) << 4);
}

// ---------- K0: bf16 weight tables + epilogue constant
// a1cat[208][640]: k<300 -> Att1[300+k][e], k in [320,620) -> Att1[k-320][e],
//                  k==620 -> ba1[e], else 0
// f2t[208][640] = fuse2[d][e]
// wg9[c][960][32]: rows G*320+j; f<8 = Wih gate weight, f==8 = b_ih+b_hh, f>8 = 0
// kconst = sum_e bf2[e]*Wout[e] + bout
__global__ __launch_bounds__(256) void k_prep(
    const float* __restrict__ Att1, const float* __restrict__ ba1,
    const float* __restrict__ fuse2, const float* __restrict__ bf2,
    const float* __restrict__ Wout, const float* __restrict__ bout,
    const float* __restrict__ Wih, const float* __restrict__ bih,
    const float* __restrict__ bhh,
    unsigned short* __restrict__ a1cat, unsigned short* __restrict__ f2t,
    unsigned short* __restrict__ wg9, float* __restrict__ kconst)
{
  int bid = blockIdx.x, tid = threadIdx.x;
  if (bid == 2480){
    __shared__ float red[256];
    red[tid] = (tid < 200) ? bf2[tid]*Wout[tid] : 0.f;
    __syncthreads();
    for (int s=128; s>0; s>>=1){
      if (tid < s) red[tid] += red[tid+s];
      __syncthreads();
    }
    if (tid == 0) kconst[0] = red[0] + bout[0];
    return;
  }
  int id = bid*256 + tid;
  if (id < 133120){
    int e = id / 640, k = id - e*640;
    float v = 0.f;
    if (e < 200){
      if (k < 300)                  v = Att1[(size_t)(300+k)*200 + e];
      else if (k >= 320 && k < 620) v = Att1[(size_t)(k-320)*200 + e];
      else if (k == 620)            v = ba1[e];
    }
    a1cat[id] = f2bf(v);
  } else if (id < 266240){
    int j = id - 133120, e = j/K6K, d = j - e*K6K;
    float v = (e<200 && d<600) ? fuse2[(size_t)d*200 + e] : 0.f;
    f2t[j] = f2bf(v);
  } else {
    int idx = id - 266240;   // < 368640 = 12*960*32
    int c = idx / 30720, rem = idx - c*30720;
    int row = rem >> 5, f = rem & 31;
    int G = row / 320, j = row - G*320;
    int off = (G==0) ? 0 : (G==1) ? 600 : 900;
    float v = 0.f;
    if (j < 300){
      if (f < 8)       v = Wih[(size_t)c*9600 + (size_t)(off+j)*8 + f];
      else if (f == 8) v = bih[c*1200+off+j] + bhh[c*1200+off+j];
    }
    wg9[idx] = f2bf(v);
  }
}

// ---------- K0b: Sbf9[c][p][32]: f<8 = bf16(S[p][f][c]), f==8 = 1.0, else 0
__global__ __launch_bounds__(256) void k_sprep(
    const float* __restrict__ li, unsigned short* __restrict__ Sbf9)
{
  int pb0 = blockIdx.x * 8;
  int tid = threadIdx.x;
  __shared__ float s_li[8*240];
  for (int i = tid; i < 8*240; i += 256)
    s_li[i] = li[(size_t)pb0*240 + i];
  __syncthreads();
  for (int i = tid; i < 8*384; i += 256){
    int pp = i / 384, rem = i - pp*384;
    int c = rem >> 5, f = rem & 31;
    unsigned short v = 0;
    if (f < 8)       v = f2bf(s_li[pp*240 + f*12 + c]);
    else if (f == 8) v = 0x3F80;   // 1.0 bf16 (bias lane)
    Sbf9[(((size_t)c*NP + pb0 + pp) << 5) + f] = v;
  }
}

// ---------- K1: htarget bf16 [8192][320]; col 300 = 1.0 (ba1 fold), 301..319 = 0
#define HTP 16
__global__ __launch_bounds__(320) void k_htarget(
    const float* __restrict__ extras, const float* __restrict__ Wt,
    const float* __restrict__ bti, const float* __restrict__ bth,
    unsigned short* __restrict__ htpad)
{
  int p0 = blockIdx.x * HTP;
  int tid = threadIdx.x;
  __shared__ float s_e[HTP][5];
  if (tid < HTP*5) s_e[tid/5][tid%5] = extras[(size_t)(p0 + tid/5)*17 + (tid%5)];
  __syncthreads();
  int j = tid;
  if (j < 300){
    float w[15];
    #pragma unroll
    for (int f=0; f<5; f++){
      w[f]    = Wt[(size_t)j*5 + f];
      w[5+f]  = Wt[(size_t)(j+600)*5 + f];
      w[10+f] = Wt[(size_t)(j+900)*5 + f];
    }
    float bi = bti[j]     + bth[j];
    float bg = bti[j+600] + bth[j+600];
    float bo = bti[j+900] + bth[j+900];
    for (int pp=0; pp<HTP; pp++){
      float gi=bi, gg=bg, go=bo;
      #pragma unroll
      for (int f=0; f<5; f++){
        float t = s_e[pp][f];
        gi += t*w[f]; gg += t*w[5+f]; go += t*w[10+f];
      }
      float cc = fsig(gi)*ftanh(gg);
      htpad[(size_t)(p0+pp)*KPAD + j] = rbf(fsig(go)*ftanh(cc));
    }
  } else {
    unsigned short v = (j == 300) ? (unsigned short)0x3F80 : (unsigned short)0;
    for (int pp=0; pp<HTP; pp++)
      htpad[(size_t)(p0+pp)*KPAD + j] = v;
  }
}

// ---------- K2: transposed bias-folded gate MFMA + concat score GEMM
// block: c = bid>>7, 64 consecutive p.  h stored hpad2[(c*8192+p)*320+j]
__global__ __launch_bounds__(256, 4) void k_hs(
    const float* __restrict__ li, const unsigned short* __restrict__ Sbf9,
    const unsigned short* __restrict__ wg9,
    const unsigned short* __restrict__ a1cat,
    const unsigned short* __restrict__ htpad,
    const float* __restrict__ att2, const float* __restrict__ ba2,
    unsigned short* __restrict__ hpad2, float* __restrict__ score)
{
  int c  = blockIdx.x >> 7;
  int p0 = (blockIdx.x & 127) << 6;
  int tid = threadIdx.x;
  int wave = tid >> 6, lane = tid & 63;
  int lr = lane & 15, lg = lane >> 4;
  __shared__ __align__(16) unsigned short s_h[64*KPAD];  // 40960 B

  f32x4 zero4 = (f32x4){0.f,0.f,0.f,0.f};
  // S-frag (B operand): this wave's 16 p-cols, K=32 row (9 real), loop-invariant
  short8 sfrag = *(const short8*)(Sbf9 + (((size_t)c*NP + p0 + wave*16 + lr) << 5) + lg*8);
  const unsigned short* wbase = wg9 + (size_t)c*960*32;

  // phase 1: gates^T via MFMA; lane owns 4 consecutive j for one p -> ds_write_b64
  short8 nw0 = *(const short8*)(wbase + ((size_t)(      lr) << 5) + lg*8);
  short8 nw1 = *(const short8*)(wbase + ((size_t)(320 + lr) << 5) + lg*8);
  short8 nw2 = *(const short8*)(wbase + ((size_t)(640 + lr) << 5) + lg*8);
  int srow = wave*16 + lr;           // s_h row = p-in-block
  for (int ch = 0; ch < 20; ch++){
    int n0 = ch*16;
    short8 cw0 = nw0, cw1 = nw1, cw2 = nw2;
    if (ch < 19){
      int nr = n0 + 16 + lr;
      nw0 = *(const short8*)(wbase + ((size_t)(      nr) << 5) + lg*8);
      nw1 = *(const short8*)(wbase + ((size_t)(320 + nr) << 5) + lg*8);
      nw2 = *(const short8*)(wbase + ((size_t)(640 + nr) << 5) + lg*8);
    }
    f32x4 gi4 = __builtin_amdgcn_mfma_f32_16x16x32_bf16(cw0, sfrag, zero4, 0, 0, 0);
    f32x4 gg4 = __builtin_amdgcn_mfma_f32_16x16x32_bf16(cw1, sfrag, zero4, 0, 0, 0);
    f32x4 go4 = __builtin_amdgcn_mfma_f32_16x16x32_bf16(cw2, sfrag, zero4, 0, 0, 0);
    short4v pk;
    #pragma unroll
    for (int i=0; i<4; i++){
      float cc = fsig(gi4[i])*ftanh(gg4[i]);
      float hv = fsig(go4[i])*ftanh(cc);
      pk[i] = (short)rbf(hv);
    }
    *(short4v*)((char*)s_h + swzb(srow, n0 + lg*4, KPAD)) = pk;
  }
  __syncthreads();

  // dump s_h -> hpad2 (16B coalesced; swizzle permutes whole 16B blocks)
  unsigned short* gout = hpad2 + (size_t)(c*8192 + p0)*KPAD;
  for (int idx = tid; idx < 64*40; idx += 256){
    int row = idx / 40, c16 = idx - row*40;
    short8 v = *(const short8*)((char*)s_h + swzb(row, c16*8, KPAD));
    *(short8*)&gout[(size_t)row*KPAD + c16*8] = v;
  }

  // phase 2: concat GEMM K=640 (k<320: h from LDS, k>=320: ht from global)
  // wave w owns nt = w + 4*t4; all 4 m-tiles
  f32x4 acc[4][4];
  #pragma unroll
  for (int mt=0; mt<4; mt++)
    #pragma unroll
    for (int t4=0; t4<4; t4++) acc[mt][t4] = zero4;
  for (int k0=0; k0<KCAT; k0+=32){
    short8 a[4];
    if (k0 < KPAD){
      #pragma unroll
      for (int mt=0; mt<4; mt++)
        a[mt] = *(const short8*)((char*)s_h + swzb(mt*16 + lr, lg*8 + k0, KPAD));
    } else {
      #pragma unroll
      for (int mt=0; mt<4; mt++)
        a[mt] = *(const short8*)(htpad + (size_t)(p0 + mt*16 + lr)*KPAD + (k0 - KPAD) + lg*8);
    }
    #pragma unroll
    for (int t4=0; t4<4; t4++){
      int nt = wave + t4*4;
      if (nt < NTI){
        short8 b = *(const short8*)(a1cat + (size_t)(nt*16 + lr)*KCAT + lg*8 + k0);
        #pragma unroll
        for (int mt=0; mt<4; mt++)
          acc[mt][t4] = __builtin_amdgcn_mfma_f32_16x16x32_bf16(a[mt], b, acc[mt][t4], 0, 0, 0);
      }
    }
  }

  // epilogue: relu(acc) . att2  (ba1/ta already inside acc)
  float sacc[4][4];
  #pragma unroll
  for (int mt=0; mt<4; mt++)
    #pragma unroll
    for (int i=0; i<4; i++) sacc[mt][i] = 0.f;
  #pragma unroll
  for (int t4=0; t4<4; t4++){
    int nt = wave + t4*4;
    if (nt < NTI){
      int e = nt*16 + lr;
      if (e < 200){
        float a2v = att2[e];
        #pragma unroll
        for (int mt=0; mt<4; mt++)
          #pragma unroll
          for (int i=0; i<4; i++)
            sacc[mt][i] += fmaxf(acc[mt][t4][i], 0.f) * a2v;
      }
    }
  }
  __syncthreads();                       // s_h reads done; safe to alias
  float* s_red = reinterpret_cast<float*>(s_h);   // [4][64]
  #pragma unroll
  for (int mt=0; mt<4; mt++){
    #pragma unroll
    for (int i=0; i<4; i++){
      float s = sacc[mt][i];
      s += __shfl_xor(s, 1);
      s += __shfl_xor(s, 2);
      s += __shfl_xor(s, 4);
      s += __shfl_xor(s, 8);
      if (lr == 0) s_red[wave*64 + mt*16 + lg*4 + i] = s;
    }
  }
  __syncthreads();
  if (tid < 64){
    float r = s_red[tid] + s_red[64+tid] + s_red[128+tid] + s_red[192+tid];
    int p = p0 + tid;
    float w200 = att2[200], w201 = att2[201], b2 = ba2[0];
    float w0 = li[(size_t)p*240 + 84 + c];   // local_inputs[p,7,c]
    float w1 = li[(size_t)p*240 + 72 + c];   // local_inputs[p,6,c]
    score[(size_t)p*NCH + c] = fmaxf(r + w0*w200 + w1*w201 + b2, 0.f);
  }
}

// ---------- K3: softmax over channels -> wsoft[t][c][b]
__global__ void k_softmax(const float* __restrict__ score, float* __restrict__ wsoft)
{
  int t = blockIdx.x;
  int b = threadIdx.x;
  const float* s = score + ((size_t)b*NTT + t)*NCH;
  float v[NCH];
  float m = -1e30f;
  #pragma unroll
  for (int c=0; c<NCH; c++){ v[c] = s[c]; m = fmaxf(m, v[c]); }
  float sum = 0.f;
  #pragma unroll
  for (int c=0; c<NCH; c++){ v[c] = __expf(v[c]-m); sum += v[c]; }
  float inv = __builtin_amdgcn_rcpf(sum);
  #pragma unroll
  for (int c=0; c<NCH; c++)
    wsoft[((size_t)t*NCH + c)*NB + b] = v[c]*inv;
}

// ---------- K4: fusion build (bf16 LDS) + MFMA vs fuse2^T + Wout dot
#define K6P 16
__global__ __launch_bounds__(256) void k_out(
    const unsigned short* __restrict__ hpad2, const unsigned short* __restrict__ htpad,
    const float* __restrict__ wsoft, const unsigned short* __restrict__ f2t,
    const float* __restrict__ Wout, const float* __restrict__ kconst,
    const float* __restrict__ labels, float* __restrict__ out)
{
  int p0 = blockIdx.x * K6P;
  int tid = threadIdx.x;
  __shared__ float s_w[K6P][NCH];
  __shared__ __align__(16) unsigned short s_f[K6P*K6K];   // swizzled, stride 1280B
  __shared__ float s_red[4][K6P];

  for (int i = tid; i < K6P*NCH; i += 256){
    int ps = i / NCH, c = i - ps*NCH;
    int p = p0 + ps;
    int b = p >> 6, t = p & 63;
    int idx = b*NCH + c;            // reference reshape scramble
    s_w[ps][c] = wsoft[((size_t)t*NCH + (idx>>7))*NB + (idx & 127)];
  }
  __syncthreads();

  // fusion[p][0:300]=sum_c h*w ; [300:600]=htarget ; [600:640]=0
  for (int it = tid; it < K6P*(K6K/8); it += 256){
    int ps = it / (K6K/8);
    int d0 = (it - ps*(K6K/8)) * 8;
    int p  = p0 + ps;
    unsigned short pk[8];
    if (d0 <= 288){                       // pure h part (d0+7 <= 295 < 300)
      float a8[8];
      #pragma unroll
      for (int k=0; k<8; k++) a8[k] = 0.f;
      #pragma unroll
      for (int c=0; c<NCH; c++){
        short8 v = *(const short8*)(hpad2 + (size_t)(c*8192 + p)*KPAD + d0);
        float wc = s_w[ps][c];
        #pragma unroll
        for (int k=0; k<8; k++) a8[k] += bf2f((unsigned short)v[k]) * wc;
      }
      #pragma unroll
      for (int k=0; k<8; k++) pk[k] = rbf(a8[k]);
    } else if (d0 == 296){                // mixed boundary 296..303
      #pragma unroll
      for (int k=0; k<8; k++){
        int d = 296 + k;
        if (d < 300){
          float v = 0.f;
          #pragma unroll
          for (int c=0; c<NCH; c++)
            v += bf2f(hpad2[(size_t)(c*8192 + p)*KPAD + d]) * s_w[ps][c];
          pk[k] = rbf(v);
        } else {
          pk[k] = htpad[(size_t)p*KPAD + (d - 300)];
        }
      }
    } else if (d0 < 600){                 // pure htarget (304..592)
      const unsigned short* hp = htpad + (size_t)p*KPAD + (d0 - 300);
      short4v v0 = *(const short4v*)hp;
      short4v v1 = *(const short4v*)(hp + 4);
      #pragma unroll
      for (int k=0; k<4; k++){ pk[k] = (unsigned short)v0[k]; pk[4+k] = (unsigned short)v1[k]; }
    } else {
      #pragma unroll
      for (int k=0; k<8; k++) pk[k] = 0;
    }
    short8 o;
    #pragma unroll
    for (int k=0; k<8; k++) o[k] = (short)pk[k];
    *(short8*)((char*)s_f + swzb(ps, d0, K6K)) = o;
  }
  __syncthreads();

  // GEMM: [16 x 640] x [640 x 208], wave w owns nt = w, w+4, w+8, (w==0: 12)
  int wave = tid >> 6, lane = tid & 63;
  int lr = lane & 15, lg = lane >> 4;
  f32x4 acc[4];
  #pragma unroll
  for (int t4=0; t4<4; t4++) acc[t4] = (f32x4){0.f,0.f,0.f,0.f};
  for (int k0=0; k0<K6K; k0+=32){
    short8 a = *(const short8*)((char*)s_f + swzb(lr, lg*8 + k0, K6K));
    #pragma unroll
    for (int t4=0; t4<4; t4++){
      int nt = wave + t4*4;
      if (nt < NTI){
        short8 b = *(const short8*)(f2t + (size_t)(nt*16 + lr)*K6K + lg*8 + k0);
        acc[t4] = __builtin_amdgcn_mfma_f32_16x16x32_bf16(a, b, acc[t4], 0, 0, 0);
      }
    }
  }
  float part[4] = {0.f,0.f,0.f,0.f};
  #pragma unroll
  for (int t4=0; t4<4; t4++){
    int nt = wave + t4*4;
    if (nt < NTI){
      int e = nt*16 + lr;
      float wv = (e < 200) ? Wout[e] : 0.f;
      #pragma unroll
      for (int i=0; i<4; i++) part[i] += acc[t4][i] * wv;
    }
  }
  #pragma unroll
  for (int i=0; i<4; i++){
    float s = part[i];
    s += __shfl_xor(s, 1);
    s += __shfl_xor(s, 2);
    s += __shfl_xor(s, 4);
    s += __shfl_xor(s, 8);
    if (lr == 0) s_red[wave][lg*4 + i] = s;
  }
  __syncthreads();
  if (tid < K6P){
    float sum = s_red[0][tid] + s_red[1][tid] + s_red[2][tid] + s_red[3][tid] + kconst[0];
    int p = p0 + tid;
    int b = p >> 6, t = p & 63;
    out[(size_t)t*NB + b] = sum;
    out[NP + (size_t)t*NB + b] = labels[p];
  }
}

extern "C" void kernel_launch(void* const* d_in, const int* in_sizes, int n_in,
                              void* d_out, int out_size, void* d_ws, size_t ws_size,
                              hipStream_t stream)
{
  const float* li     = (const float*)d_in[0];
  const float* labels = (const float*)d_in[1];
  const float* extras = (const float*)d_in[2];
  const float* Wih    = (const float*)d_in[5];
  const float* bih    = (const float*)d_in[6];
  const float* bhh    = (const float*)d_in[7];
  const float* Wt     = (const float*)d_in[8];
  const float* bti    = (const float*)d_in[9];
  const float* bth    = (const float*)d_in[10];
  const float* Att1   = (const float*)d_in[11];
  const float* ba1    = (const float*)d_in[12];
  const float* Att2   = (const float*)d_in[13];
  const float* ba2    = (const float*)d_in[14];
  const float* fuse2  = (const float*)d_in[15];
  const float* bf2    = (const float*)d_in[16];
  const float* Wout   = (const float*)d_in[17];
  const float* bout   = (const float*)d_in[18];
  float* out = (float*)d_out;

  char* ws = (char*)d_ws;
  unsigned short* hpad2 = (unsigned short*)ws;                      // 62,914,560
  unsigned short* htpad = (unsigned short*)(ws + 62914560);         //  5,242,880
  float* score  = (float*)(ws + 68157440);                          //    393,216
  float* wsoft  = (float*)(ws + 68550656);                          //    393,216
  unsigned short* a1cat = (unsigned short*)(ws + 68943872);         //    266,240
  unsigned short* f2t   = (unsigned short*)(ws + 69210112);         //    266,240
  unsigned short* wg9   = (unsigned short*)(ws + 69476352);         //    737,280
  unsigned short* Sbf9  = (unsigned short*)(ws + 70213632);         //  6,291,456
  float* kconst = (float*)(ws + 76505088);                          //          4

  k_prep<<<2481, 256, 0, stream>>>(Att1, ba1, fuse2, bf2, Wout, bout,
                                   Wih, bih, bhh, a1cat, f2t, wg9, kconst);
  k_sprep<<<NP/8, 256, 0, stream>>>(li, Sbf9);
  k_htarget<<<NP/HTP, 320, 0, stream>>>(extras, Wt, bti, bth, htpad);
  k_hs<<<NCH*128, 256, 0, stream>>>(li, Sbf9, wg9, a1cat, htpad, Att2, ba2,
                                    hpad2, score);
  k_softmax<<<NTT, NB, 0, stream>>>(score, wsoft);
  k_out<<<NP/K6P, 256, 0, stream>>>(hpad2, htpad, wsoft, f2t, Wout, kconst,
                                    labels, out);
}

// Round 9
// 218.373 us; speedup vs baseline: 1.1408x; 1.1408x over previous
//
#include <hip/hip_runtime.h>
#include <hip/hip_bf16.h>

#define HH   300
#define NB   128
#define NTT  64
#define NP   8192        // B*T
#define NCH  12
#define KPAD 320         // padded K (300 -> 320)
#define NTI2 14          // 13 e-tiles + 1 g-tile (H / T column at e=208)

typedef __attribute__((ext_vector_type(8))) short short8;
typedef __attribute__((ext_vector_type(4))) float f32x4;

__device__ __forceinline__ float fsig(float x){
  return __builtin_amdgcn_rcpf(1.f + __expf(-x));
}
__device__ __forceinline__ float ftanh(float x){
  float e = __expf(2.f*x);
  return 1.f - 2.f*__builtin_amdgcn_rcpf(e + 1.f);   // safe at +/-inf
}
__device__ __forceinline__ float bf2f(unsigned short u){
  return __uint_as_float(((unsigned)u) << 16);
}
__device__ __forceinline__ unsigned short f2bf(float f){      // RNE
  __hip_bfloat16 h = __float2bfloat16(f);
  return *reinterpret_cast<unsigned short*>(&h);
}
__device__ __forceinline__ unsigned short rbf(float f){       // round-half-up
  return (unsigned short)((__float_as_uint(f) + 0x8000u) >> 16);
}
// XOR-swizzled LDS short-index; strideShorts*2 must be a multiple of 128B
__device__ __forceinline__ int swzi(int row, int col, int strideShorts){
  int byte = row*(strideShorts*2) + (col<<1);
  byte ^= (row & 7) << 4;
  return byte >> 1;
}

// ---------- K-1: g[d] = sum_e fuse2[d][e]*Wout[e] (600 f32); kconst
__global__ __launch_bounds__(256) void k_gvec(
    const float* __restrict__ fuse2, const float* __restrict__ bf2,
    const float* __restrict__ Wout, const float* __restrict__ bout,
    float* __restrict__ gbuf, float* __restrict__ kconst)
{
  int tid = threadIdx.x;
  if (blockIdx.x == 3){
    __shared__ float red[256];
    red[tid] = (tid < 200) ? bf2[tid]*Wout[tid] : 0.f;
    __syncthreads();
    for (int s=128; s>0; s>>=1){
      if (tid < s) red[tid] += red[tid+s];
      __syncthreads();
    }
    if (tid == 0) kconst[0] = red[0] + bout[0];
    return;
  }
  int d = blockIdx.x*256 + tid;
  if (d < 600){
    const float* fr = fuse2 + (size_t)d*200;
    float a = 0.f;
    #pragma unroll 4
    for (int e=0; e<200; e++) a += fr[e]*Wout[e];
    gbuf[d] = a;
  }
}

// ---------- K0: bf16 tables.
// a1hi2[224][320]: row e<200: k<300 -> Att1[300+k][e]; row 208: k<300 -> g[k]; else 0
// a1lo2[224][320]: row e<200: k<300 -> Att1[k][e], k==300 -> ba1[e];
//                  row 208: k<300 -> g[300+k]; else 0
// wg3[c][960][8]: i/g/o gate weights (j padded 300->320 with 0)
// bsum3[c][960]:  b_ih+b_hh (padded 0)
__global__ __launch_bounds__(256) void k_prep(
    const float* __restrict__ Att1, const float* __restrict__ ba1,
    const float* __restrict__ Wih, const float* __restrict__ bih,
    const float* __restrict__ bhh, const float* __restrict__ gbuf,
    unsigned short* __restrict__ a1hi2, unsigned short* __restrict__ a1lo2,
    unsigned short* __restrict__ wg3, float* __restrict__ bsum3)
{
  int id = blockIdx.x*256 + threadIdx.x;
  if (id < 71680){
    int e = id/320, k = id - e*320;
    float v = 0.f;
    if (e < 200 && k < 300)        v = Att1[(size_t)(300+k)*200 + e];
    else if (e == 208 && k < 300)  v = gbuf[k];
    a1hi2[id] = f2bf(v);
  } else if (id < 143360){
    int j = id - 71680;
    int e = j/320, k = j - e*320;
    float v = 0.f;
    if (e < 200){
      if (k < 300)       v = Att1[(size_t)k*200 + e];
      else if (k == 300) v = ba1[e];
    } else if (e == 208 && k < 300) v = gbuf[300+k];
    a1lo2[j] = f2bf(v);
  } else if (id < 235520){
    int idx = id - 143360;
    int c = idx / 7680, rem = idx - c*7680;
    int np = rem >> 3, f = rem & 7;
    int G = np / 320, j = np - G*320;
    int off = (G==0) ? 0 : (G==1) ? 600 : 900;
    float v = (j<300) ? Wih[(size_t)c*9600 + (size_t)(off+j)*8 + f] : 0.f;
    wg3[idx] = f2bf(v);
  } else {
    int idx = id - 235520;   // < 11520
    int c = idx / 960, np = idx - c*960;
    int G = np / 320, j = np - G*320;
    int off = (G==0) ? 0 : (G==1) ? 600 : 900;
    bsum3[idx] = (j<300) ? (bih[c*1200+off+j] + bhh[c*1200+off+j]) : 0.f;
  }
}

// ---------- K0b: Sbf[c][p][8] = bf16(li[p*240 + f*12 + c])
__global__ __launch_bounds__(256) void k_sprep(
    const float* __restrict__ li, unsigned short* __restrict__ Sbf)
{
  int pb0 = blockIdx.x * 8;
  int tid = threadIdx.x;
  __shared__ float s_li[8*240];
  for (int i = tid; i < 8*240; i += 256)
    s_li[i] = li[(size_t)pb0*240 + i];
  __syncthreads();
  for (int i = tid; i < 8*96; i += 256){
    int pp = i / 96, rem = i - pp*96;
    int c = rem >> 3, f = rem & 7;
    Sbf[((size_t)c*NP + pb0 + pp)*8 + f] = f2bf(s_li[pp*240 + f*12 + c]);
  }
}

// ---------- K1: htarget bf16 [8192][320]; col 300 = 1.0 (ba1 fold), rest 0
#define HTP 16
__global__ __launch_bounds__(320) void k_htarget(
    const float* __restrict__ extras, const float* __restrict__ Wt,
    const float* __restrict__ bti, const float* __restrict__ bth,
    unsigned short* __restrict__ htpad)
{
  int p0 = blockIdx.x * HTP;
  int tid = threadIdx.x;
  __shared__ float s_e[HTP][5];
  if (tid < HTP*5) s_e[tid/5][tid%5] = extras[(size_t)(p0 + tid/5)*17 + (tid%5)];
  __syncthreads();
  int j = tid;
  if (j < 300){
    float w[15];
    #pragma unroll
    for (int f=0; f<5; f++){
      w[f]    = Wt[(size_t)j*5 + f];
      w[5+f]  = Wt[(size_t)(j+600)*5 + f];
      w[10+f] = Wt[(size_t)(j+900)*5 + f];
    }
    float bi = bti[j]     + bth[j];
    float bg = bti[j+600] + bth[j+600];
    float bo = bti[j+900] + bth[j+900];
    for (int pp=0; pp<HTP; pp++){
      float gi=bi, gg=bg, go=bo;
      #pragma unroll
      for (int f=0; f<5; f++){
        float t = s_e[pp][f];
        gi += t*w[f]; gg += t*w[5+f]; go += t*w[10+f];
      }
      float cc = fsig(gi)*ftanh(gg);
      htpad[(size_t)(p0+pp)*KPAD + j] = rbf(fsig(go)*ftanh(cc));
    }
  } else {
    unsigned short v = (j == 300) ? (unsigned short)0x3F80 : (unsigned short)0;
    for (int pp=0; pp<HTP; pp++)
      htpad[(size_t)(p0+pp)*KPAD + j] = v;
  }
}

// ---------- K2: ta[p][e] (= ht.Att1lo + ba1) and T[p] (= ht.g[300:]) via MFMA
__global__ __launch_bounds__(64) void k_ta(
    const unsigned short* __restrict__ htpad,
    const unsigned short* __restrict__ a1lo2,
    float* __restrict__ ta, float* __restrict__ Tbuf)
{
  int lane = threadIdx.x;
  int lr = lane & 15, lg = lane >> 4;
  int r0 = blockIdx.x*16;
  f32x4 acc[NTI2];
  #pragma unroll
  for (int nt=0; nt<NTI2; nt++) acc[nt] = (f32x4){0.f,0.f,0.f,0.f};
  const unsigned short* ap = htpad + (size_t)(r0+lr)*KPAD + lg*8;
  const unsigned short* bp = a1lo2 + (size_t)lr*KPAD + lg*8;
  for (int k0=0; k0<KPAD; k0+=32){
    short8 a = *(const short8*)(ap + k0);
    #pragma unroll
    for (int nt=0; nt<NTI2; nt++){
      short8 b = *(const short8*)(bp + (size_t)nt*16*KPAD + k0);
      acc[nt] = __builtin_amdgcn_mfma_f32_16x16x32_bf16(a, b, acc[nt], 0, 0, 0);
    }
  }
  #pragma unroll
  for (int nt=0; nt<13; nt++){
    int e = nt*16 + lr;
    if (e < 200){
      #pragma unroll
      for (int i=0; i<4; i++)
        ta[(size_t)(r0 + lg*4 + i)*200 + e] = acc[nt][i];
    }
  }
  if (lr == 0){              // tile 13, col e=208 -> T[p]
    #pragma unroll
    for (int i=0; i<4; i++)
      Tbuf[r0 + lg*4 + i] = acc[13][i];
  }
}

// ---------- K3: gate MFMA -> h in LDS -> score GEMM (+H column), NO h dump
// block: c = bid>>7, 64 consecutive p.
__global__ __launch_bounds__(256, 4) void k_hs(
    const float* __restrict__ li, const unsigned short* __restrict__ Sbf,
    const unsigned short* __restrict__ wg3, const float* __restrict__ bsum3,
    const unsigned short* __restrict__ a1hi2, const float* __restrict__ ta,
    const float* __restrict__ att2, const float* __restrict__ ba2,
    float* __restrict__ Hbuf, float* __restrict__ score)
{
  int c  = blockIdx.x >> 7;
  int p0 = (blockIdx.x & 127) << 6;
  int tid = threadIdx.x;
  int wave = tid >> 6, lane = tid & 63;
  int lr = lane & 15, lg = lane >> 4;
  __shared__ __align__(16) unsigned short s_h[64*KPAD];  // 40960 B

  short8 z8 = (short8){0,0,0,0,0,0,0,0};
  short8 afrag = z8;
  if (lg == 0)
    afrag = *(const short8*)(Sbf + ((size_t)c*NP + p0 + wave*16 + lr)*8);

  // phase 1: gates via MFMA (K=8 in lg==0 slot) + elementwise tail
  const unsigned short* wgc = wg3 + (size_t)c*960*8;
  const float* bsc = bsum3 + (size_t)c*960;
  f32x4 zero4 = (f32x4){0.f,0.f,0.f,0.f};
  int rowb = wave*16 + lg*4;
  short8 nb0 = z8, nb1 = z8, nb2 = z8;
  if (lg == 0){
    nb0 = *(const short8*)&wgc[(size_t)(      lr)*8];
    nb1 = *(const short8*)&wgc[(size_t)(320 + lr)*8];
    nb2 = *(const short8*)&wgc[(size_t)(640 + lr)*8];
  }
  for (int ch = 0; ch < 20; ch++){
    int n0 = ch*16;
    short8 cb0 = nb0, cb1 = nb1, cb2 = nb2;
    if (ch < 19 && lg == 0){
      int nn = n0 + 16 + lr;
      nb0 = *(const short8*)&wgc[(size_t)(      nn)*8];
      nb1 = *(const short8*)&wgc[(size_t)(320 + nn)*8];
      nb2 = *(const short8*)&wgc[(size_t)(640 + nn)*8];
    }
    f32x4 gi4 = __builtin_amdgcn_mfma_f32_16x16x32_bf16(afrag, cb0, zero4, 0, 0, 0);
    f32x4 gg4 = __builtin_amdgcn_mfma_f32_16x16x32_bf16(afrag, cb1, zero4, 0, 0, 0);
    f32x4 go4 = __builtin_amdgcn_mfma_f32_16x16x32_bf16(afrag, cb2, zero4, 0, 0, 0);
    float bi = bsc[      n0 + lr];
    float bg = bsc[320 + n0 + lr];
    float bo = bsc[640 + n0 + lr];
    #pragma unroll
    for (int i2=0; i2<4; i2++){
      float gi = gi4[i2] + bi;
      float gg = gg4[i2] + bg;
      float go = go4[i2] + bo;
      float cc = fsig(gi)*ftanh(gg);
      float hv = fsig(go)*ftanh(cc);
      s_h[swzi(rowb + i2, n0 + lr, KPAD)] = rbf(hv);
    }
  }
  __syncthreads();

  // phase 2: n-split K=320 GEMM; wave w owns nt = w + 4*t4 (<14); 4 m-tiles
  f32x4 acc[4][4];
  #pragma unroll
  for (int mt=0; mt<4; mt++)
    #pragma unroll
    for (int t4=0; t4<4; t4++) acc[mt][t4] = zero4;
  for (int k0=0; k0<KPAD; k0+=32){
    short8 a[4];
    #pragma unroll
    for (int mt=0; mt<4; mt++)
      a[mt] = *(const short8*)&s_h[swzi(mt*16 + lr, lg*8 + k0, KPAD)];
    #pragma unroll
    for (int t4=0; t4<4; t4++){
      int nt = wave + t4*4;
      if (nt < NTI2){
        short8 b = *(const short8*)(a1hi2 + (size_t)(nt*16 + lr)*KPAD + lg*8 + k0);
        #pragma unroll
        for (int mt=0; mt<4; mt++)
          acc[mt][t4] = __builtin_amdgcn_mfma_f32_16x16x32_bf16(a[mt], b, acc[mt][t4], 0, 0, 0);
      }
    }
  }

  // epilogue: score partials (ta includes ba1) + H writes (nt==13, e=208)
  float sacc[4][4];
  #pragma unroll
  for (int mt=0; mt<4; mt++)
    #pragma unroll
    for (int i=0; i<4; i++) sacc[mt][i] = 0.f;
  #pragma unroll
  for (int t4=0; t4<4; t4++){
    int nt = wave + t4*4;
    if (nt < 13){
      int e = nt*16 + lr;
      if (e < 200){
        float a2v = att2[e];
        #pragma unroll
        for (int mt=0; mt<4; mt++){
          #pragma unroll
          for (int i=0; i<4; i++){
            int p = p0 + mt*16 + lg*4 + i;
            float v = acc[mt][t4][i] + ta[(size_t)p*200 + e];
            sacc[mt][i] += fmaxf(v, 0.f) * a2v;
          }
        }
      }
    } else if (nt == 13 && lr == 0){
      #pragma unroll
      for (int mt=0; mt<4; mt++)
        #pragma unroll
        for (int i=0; i<4; i++)
          Hbuf[(size_t)(p0 + mt*16 + lg*4 + i)*NCH + c] = acc[mt][t4][i];
    }
  }
  __syncthreads();                       // s_h reads done; safe to alias
  float* s_red = reinterpret_cast<float*>(s_h);   // [4][64]
  #pragma unroll
  for (int mt=0; mt<4; mt++){
    #pragma unroll
    for (int i=0; i<4; i++){
      float s = sacc[mt][i];
      s += __shfl_xor(s, 1);
      s += __shfl_xor(s, 2);
      s += __shfl_xor(s, 4);
      s += __shfl_xor(s, 8);
      if (lr == 0) s_red[wave*64 + mt*16 + lg*4 + i] = s;
    }
  }
  __syncthreads();
  if (tid < 64){
    float r = s_red[tid] + s_red[64+tid] + s_red[128+tid] + s_red[192+tid];
    int p = p0 + tid;
    float w200 = att2[200], w201 = att2[201], b2 = ba2[0];
    float w0 = li[(size_t)p*240 + 84 + c];   // local_inputs[p,7,c]
    float w1 = li[(size_t)p*240 + 72 + c];   // local_inputs[p,6,c]
    score[(size_t)p*NCH + c] = fmaxf(r + w0*w200 + w1*w201 + b2, 0.f);
  }
}

// ---------- K4: softmax over channels -> wsoft[t][c][b]
__global__ void k_softmax(const float* __restrict__ score, float* __restrict__ wsoft)
{
  int t = blockIdx.x;
  int b = threadIdx.x;
  const float* s = score + ((size_t)b*NTT + t)*NCH;
  float v[NCH];
  float m = -1e30f;
  #pragma unroll
  for (int c=0; c<NCH; c++){ v[c] = s[c]; m = fmaxf(m, v[c]); }
  float sum = 0.f;
  #pragma unroll
  for (int c=0; c<NCH; c++){ v[c] = __expf(v[c]-m); sum += v[c]; }
  float inv = __builtin_amdgcn_rcpf(sum);
  #pragma unroll
  for (int c=0; c<NCH; c++)
    wsoft[((size_t)t*NCH + c)*NB + b] = v[c]*inv;
}

// ---------- K5: out[p] = sum_c w[p,c]*H[p,c] + T[p] + kconst; labels pass
__global__ __launch_bounds__(256) void k_final(
    const float* __restrict__ wsoft, const float* __restrict__ Hbuf,
    const float* __restrict__ Tbuf, const float* __restrict__ kconst,
    const float* __restrict__ labels, float* __restrict__ out)
{
  int p = blockIdx.x*256 + threadIdx.x;    // < NP
  int b = p >> 6, t = p & 63;
  float acc = Tbuf[p] + kconst[0];
  const float* Hp = Hbuf + (size_t)p*NCH;
  #pragma unroll
  for (int c=0; c<NCH; c++){
    int idx = b*NCH + c;                  // reference reshape scramble
    float w = wsoft[((size_t)t*NCH + (idx>>7))*NB + (idx & 127)];
    acc += w * Hp[c];
  }
  out[(size_t)t*NB + b] = acc;
  out[NP + (size_t)t*NB + b] = labels[p];
}

extern "C" void kernel_launch(void* const* d_in, const int* in_sizes, int n_in,
                              void* d_out, int out_size, void* d_ws, size_t ws_size,
                              hipStream_t stream)
{
  const float* li     = (const float*)d_in[0];
  const float* labels = (const float*)d_in[1];
  const float* extras = (const float*)d_in[2];
  const float* Wih    = (const float*)d_in[5];
  const float* bih    = (const float*)d_in[6];
  const float* bhh    = (const float*)d_in[7];
  const float* Wt     = (const float*)d_in[8];
  const float* bti    = (const float*)d_in[9];
  const float* bth    = (const float*)d_in[10];
  const float* Att1   = (const float*)d_in[11];
  const float* ba1    = (const float*)d_in[12];
  const float* Att2   = (const float*)d_in[13];
  const float* ba2    = (const float*)d_in[14];
  const float* fuse2  = (const float*)d_in[15];
  const float* bf2    = (const float*)d_in[16];
  const float* Wout   = (const float*)d_in[17];
  const float* bout   = (const float*)d_in[18];
  float* out = (float*)d_out;

  char* ws = (char*)d_ws;
  unsigned short* htpad = (unsigned short*)ws;                      //  5,242,880
  float* ta     = (float*)(ws + 5242880);                           //  6,553,600
  float* score  = (float*)(ws + 11796480);                          //    393,216
  float* wsoft  = (float*)(ws + 12189696);                          //    393,216
  float* Hbuf   = (float*)(ws + 12582912);                          //    393,216
  float* Tbuf   = (float*)(ws + 12976128);                          //     32,768
  unsigned short* a1hi2 = (unsigned short*)(ws + 13008896);         //    143,360
  unsigned short* a1lo2 = (unsigned short*)(ws + 13152256);         //    143,360
  unsigned short* wg3   = (unsigned short*)(ws + 13295616);         //    184,320
  float* bsum3  = (float*)(ws + 13479936);                          //     46,080
  unsigned short* Sbf   = (unsigned short*)(ws + 13526016);         //  1,572,864
  float* gbuf   = (float*)(ws + 15098880);                          //      2,400
  float* kconst = (float*)(ws + 15101280);                          //          4

  k_gvec<<<4, 256, 0, stream>>>(fuse2, bf2, Wout, bout, gbuf, kconst);
  k_prep<<<965, 256, 0, stream>>>(Att1, ba1, Wih, bih, bhh, gbuf,
                                  a1hi2, a1lo2, wg3, bsum3);
  k_sprep<<<NP/8, 256, 0, stream>>>(li, Sbf);
  k_htarget<<<NP/HTP, 320, 0, stream>>>(extras, Wt, bti, bth, htpad);
  k_ta<<<NP/16, 64, 0, stream>>>(htpad, a1lo2, ta, Tbuf);
  k_hs<<<NCH*128, 256, 0, stream>>>(li, Sbf, wg3, bsum3, a1hi2, ta, Att2, ba2,
                                    Hbuf, score);
  k_softmax<<<NTT, NB, 0, stream>>>(score, wsoft);
  k_final<<<NP/256, 256, 0, stream>>>(wsoft, Hbuf, Tbuf, kconst, labels, out);
}

// Round 10
// 190.212 us; speedup vs baseline: 1.3097x; 1.1481x over previous
//
#include <hip/hip_runtime.h>
#include <hip/hip_bf16.h>

#define HH   300
#define NB   128
#define NTT  64
#define NP   8192        // B*T
#define NCH  12
#define KPAD 320         // padded K (300 -> 320)
#define NTI2 14          // 13 e-tiles + 1 g-tile (H / T column at e=208)

typedef __attribute__((ext_vector_type(8))) short short8;
typedef __attribute__((ext_vector_type(4))) float f32x4;

__device__ __forceinline__ float fsig(float x){
  return __builtin_amdgcn_rcpf(1.f + __expf(-x));
}
__device__ __forceinline__ float ftanh(float x){
  float e = __expf(2.f*x);
  return 1.f - 2.f*__builtin_amdgcn_rcpf(e + 1.f);   // safe at +/-inf
}
__device__ __forceinline__ float bf2f(unsigned short u){
  return __uint_as_float(((unsigned)u) << 16);
}
__device__ __forceinline__ unsigned short f2bf(float f){      // RNE
  __hip_bfloat16 h = __float2bfloat16(f);
  return *reinterpret_cast<unsigned short*>(&h);
}
__device__ __forceinline__ unsigned short rbf(float f){       // round-half-up
  return (unsigned short)((__float_as_uint(f) + 0x8000u) >> 16);
}
// XOR-swizzled LDS short-index; strideShorts*2 must be a multiple of 128B
__device__ __forceinline__ int swzi(int row, int col, int strideShorts){
  int byte = row*(strideShorts*2) + (col<<1);
  byte ^= (row & 7) << 4;
  return byte >> 1;
}

// ---------- K0: all prep, role-split by blockIdx.
// bid < 965     : bf16 tables (a1hi2, a1lo2, wg3, bsum3), g inlined on row 208
// 965..1988     : Sbf repack (8 p per block)
// bid == 1989   : kconst = sum_e bf2[e]*Wout[e] + bout
// a1hi2[224][320]: e<200,k<300 -> Att1[300+k][e]; e==208,k<300 -> g[k]; else 0
// a1lo2[224][320]: e<200: k<300 -> Att1[k][e], k==300 -> ba1[e];
//                  e==208,k<300 -> g[300+k]; else 0   (g[d] = fuse2[d]·Wout)
__global__ __launch_bounds__(256) void k_prep(
    const float* __restrict__ Att1, const float* __restrict__ ba1,
    const float* __restrict__ Wih, const float* __restrict__ bih,
    const float* __restrict__ bhh, const float* __restrict__ fuse2,
    const float* __restrict__ bf2, const float* __restrict__ Wout,
    const float* __restrict__ bout, const float* __restrict__ li,
    unsigned short* __restrict__ a1hi2, unsigned short* __restrict__ a1lo2,
    unsigned short* __restrict__ wg3, float* __restrict__ bsum3,
    unsigned short* __restrict__ Sbf, float* __restrict__ kconst)
{
  int bid = blockIdx.x, tid = threadIdx.x;
  if (bid == 1989){
    __shared__ float red[256];
    red[tid] = (tid < 200) ? bf2[tid]*Wout[tid] : 0.f;
    __syncthreads();
    for (int s=128; s>0; s>>=1){
      if (tid < s) red[tid] += red[tid+s];
      __syncthreads();
    }
    if (tid == 0) kconst[0] = red[0] + bout[0];
    return;
  }
  if (bid >= 965){                      // Sbf repack
    int pb0 = (bid - 965) * 8;
    __shared__ float s_li[8*240];
    for (int i = tid; i < 8*240; i += 256)
      s_li[i] = li[(size_t)pb0*240 + i];
    __syncthreads();
    for (int i = tid; i < 8*96; i += 256){
      int pp = i / 96, rem = i - pp*96;
      int c = rem >> 3, f = rem & 7;
      Sbf[((size_t)c*NP + pb0 + pp)*8 + f] = f2bf(s_li[pp*240 + f*12 + c]);
    }
    return;
  }
  int id = bid*256 + tid;
  if (id < 71680){
    int e = id/320, k = id - e*320;
    float v = 0.f;
    if (e < 200 && k < 300){
      v = Att1[(size_t)(300+k)*200 + e];
    } else if (e == 208 && k < 300){
      const float* fr = fuse2 + (size_t)k*200;
      float a = 0.f;
      #pragma unroll 4
      for (int e2=0; e2<200; e2++) a += fr[e2]*Wout[e2];
      v = a;
    }
    a1hi2[id] = f2bf(v);
  } else if (id < 143360){
    int j = id - 71680;
    int e = j/320, k = j - e*320;
    float v = 0.f;
    if (e < 200){
      if (k < 300)       v = Att1[(size_t)k*200 + e];
      else if (k == 300) v = ba1[e];
    } else if (e == 208 && k < 300){
      const float* fr = fuse2 + (size_t)(300+k)*200;
      float a = 0.f;
      #pragma unroll 4
      for (int e2=0; e2<200; e2++) a += fr[e2]*Wout[e2];
      v = a;
    }
    a1lo2[j] = f2bf(v);
  } else if (id < 235520){
    int idx = id - 143360;
    int c = idx / 7680, rem = idx - c*7680;
    int np = rem >> 3, f = rem & 7;
    int G = np / 320, j = np - G*320;
    int off = (G==0) ? 0 : (G==1) ? 600 : 900;
    float v = (j<300) ? Wih[(size_t)c*9600 + (size_t)(off+j)*8 + f] : 0.f;
    wg3[idx] = f2bf(v);
  } else {
    int idx = id - 235520;   // < 11520
    int c = idx / 960, np = idx - c*960;
    int G = np / 320, j = np - G*320;
    int off = (G==0) ? 0 : (G==1) ? 600 : 900;
    bsum3[idx] = (j<300) ? (bih[c*1200+off+j] + bhh[c*1200+off+j]) : 0.f;
  }
}

// ---------- K1: fused htarget-gen (LDS) + ta/T MFMA GEMM. 32 p per block.
#define PB 32
__global__ __launch_bounds__(320) void k_ht(
    const float* __restrict__ extras, const float* __restrict__ Wt,
    const float* __restrict__ bti, const float* __restrict__ bth,
    const unsigned short* __restrict__ a1lo2,
    float* __restrict__ ta, float* __restrict__ Tbuf)
{
  int p0 = blockIdx.x * PB;
  int tid = threadIdx.x;
  __shared__ __align__(16) unsigned short s_ht[PB*KPAD];   // 20480 B
  __shared__ float s_e[PB][5];
  if (tid < PB*5) s_e[tid/5][tid%5] = extras[(size_t)(p0 + tid/5)*17 + (tid%5)];
  __syncthreads();

  int j = tid;
  if (j < 300){
    float w[15];
    #pragma unroll
    for (int f=0; f<5; f++){
      w[f]    = Wt[(size_t)j*5 + f];
      w[5+f]  = Wt[(size_t)(j+600)*5 + f];
      w[10+f] = Wt[(size_t)(j+900)*5 + f];
    }
    float bi = bti[j]     + bth[j];
    float bg = bti[j+600] + bth[j+600];
    float bo = bti[j+900] + bth[j+900];
    for (int pp=0; pp<PB; pp++){
      float gi=bi, gg=bg, go=bo;
      #pragma unroll
      for (int f=0; f<5; f++){
        float t = s_e[pp][f];
        gi += t*w[f]; gg += t*w[5+f]; go += t*w[10+f];
      }
      float cc = fsig(gi)*ftanh(gg);
      s_ht[swzi(pp, j, KPAD)] = rbf(fsig(go)*ftanh(cc));
    }
  } else {
    unsigned short v = (j == 300) ? (unsigned short)0x3F80 : (unsigned short)0;
    for (int pp=0; pp<PB; pp++)
      s_ht[swzi(pp, j, KPAD)] = v;
  }
  __syncthreads();

  // GEMM: [32 x 320] x [320 x 224]; wave w owns nt in {w, w+5, w+10} (nt<14)
  int wave = tid >> 6, lane = tid & 63;
  int lr = lane & 15, lg = lane >> 4;
  f32x4 acc[2][3];
  #pragma unroll
  for (int mt=0; mt<2; mt++)
    #pragma unroll
    for (int t=0; t<3; t++) acc[mt][t] = (f32x4){0.f,0.f,0.f,0.f};
  for (int k0=0; k0<KPAD; k0+=32){
    short8 a[2];
    #pragma unroll
    for (int mt=0; mt<2; mt++)
      a[mt] = *(const short8*)&s_ht[swzi(mt*16 + lr, lg*8 + k0, KPAD)];
    #pragma unroll
    for (int t=0; t<3; t++){
      int nt = wave + t*5;
      if (nt < NTI2){
        short8 b = *(const short8*)(a1lo2 + (size_t)(nt*16 + lr)*KPAD + lg*8 + k0);
        #pragma unroll
        for (int mt=0; mt<2; mt++)
          acc[mt][t] = __builtin_amdgcn_mfma_f32_16x16x32_bf16(a[mt], b, acc[mt][t], 0, 0, 0);
      }
    }
  }
  #pragma unroll
  for (int t=0; t<3; t++){
    int nt = wave + t*5;
    if (nt < 13){
      int e = nt*16 + lr;
      if (e < 200){
        #pragma unroll
        for (int mt=0; mt<2; mt++)
          #pragma unroll
          for (int i=0; i<4; i++)
            ta[(size_t)(p0 + mt*16 + lg*4 + i)*200 + e] = acc[mt][t][i];
      }
    } else if (nt == 13 && lr == 0){
      #pragma unroll
      for (int mt=0; mt<2; mt++)
        #pragma unroll
        for (int i=0; i<4; i++)
          Tbuf[p0 + mt*16 + lg*4 + i] = acc[mt][t][i];
    }
  }
}

// ---------- K2: gate MFMA -> h in LDS -> score GEMM (+H column)
// block: c = bid>>7, 64 consecutive p.
__global__ __launch_bounds__(256, 4) void k_hs(
    const float* __restrict__ li, const unsigned short* __restrict__ Sbf,
    const unsigned short* __restrict__ wg3, const float* __restrict__ bsum3,
    const unsigned short* __restrict__ a1hi2, const float* __restrict__ ta,
    const float* __restrict__ att2, const float* __restrict__ ba2,
    float* __restrict__ Hbuf, float* __restrict__ score)
{
  int c  = blockIdx.x >> 7;
  int p0 = (blockIdx.x & 127) << 6;
  int tid = threadIdx.x;
  int wave = tid >> 6, lane = tid & 63;
  int lr = lane & 15, lg = lane >> 4;
  __shared__ __align__(16) unsigned short s_h[64*KPAD];  // 40960 B

  short8 z8 = (short8){0,0,0,0,0,0,0,0};
  short8 afrag = z8;
  if (lg == 0)
    afrag = *(const short8*)(Sbf + ((size_t)c*NP + p0 + wave*16 + lr)*8);

  // phase 1: gates via MFMA (K=8 in lg==0 slot) + elementwise tail
  const unsigned short* wgc = wg3 + (size_t)c*960*8;
  const float* bsc = bsum3 + (size_t)c*960;
  f32x4 zero4 = (f32x4){0.f,0.f,0.f,0.f};
  int rowb = wave*16 + lg*4;
  short8 nb0 = z8, nb1 = z8, nb2 = z8;
  if (lg == 0){
    nb0 = *(const short8*)&wgc[(size_t)(      lr)*8];
    nb1 = *(const short8*)&wgc[(size_t)(320 + lr)*8];
    nb2 = *(const short8*)&wgc[(size_t)(640 + lr)*8];
  }
  for (int ch = 0; ch < 20; ch++){
    int n0 = ch*16;
    short8 cb0 = nb0, cb1 = nb1, cb2 = nb2;
    if (ch < 19 && lg == 0){
      int nn = n0 + 16 + lr;
      nb0 = *(const short8*)&wgc[(size_t)(      nn)*8];
      nb1 = *(const short8*)&wgc[(size_t)(320 + nn)*8];
      nb2 = *(const short8*)&wgc[(size_t)(640 + nn)*8];
    }
    f32x4 gi4 = __builtin_amdgcn_mfma_f32_16x16x32_bf16(afrag, cb0, zero4, 0, 0, 0);
    f32x4 gg4 = __builtin_amdgcn_mfma_f32_16x16x32_bf16(afrag, cb1, zero4, 0, 0, 0);
    f32x4 go4 = __builtin_amdgcn_mfma_f32_16x16x32_bf16(afrag, cb2, zero4, 0, 0, 0);
    float bi = bsc[      n0 + lr];
    float bg = bsc[320 + n0 + lr];
    float bo = bsc[640 + n0 + lr];
    #pragma unroll
    for (int i2=0; i2<4; i2++){
      float gi = gi4[i2] + bi;
      float gg = gg4[i2] + bg;
      float go = go4[i2] + bo;
      float cc = fsig(gi)*ftanh(gg);
      float hv = fsig(go)*ftanh(cc);
      s_h[swzi(rowb + i2, n0 + lr, KPAD)] = rbf(hv);
    }
  }
  __syncthreads();

  // phase 2: n-split K=320 GEMM; wave w owns nt = w + 4*t4 (<14); 4 m-tiles
  f32x4 acc[4][4];
  #pragma unroll
  for (int mt=0; mt<4; mt++)
    #pragma unroll
    for (int t4=0; t4<4; t4++) acc[mt][t4] = zero4;
  for (int k0=0; k0<KPAD; k0+=32){
    short8 a[4];
    #pragma unroll
    for (int mt=0; mt<4; mt++)
      a[mt] = *(const short8*)&s_h[swzi(mt*16 + lr, lg*8 + k0, KPAD)];
    #pragma unroll
    for (int t4=0; t4<4; t4++){
      int nt = wave + t4*4;
      if (nt < NTI2){
        short8 b = *(const short8*)(a1hi2 + (size_t)(nt*16 + lr)*KPAD + lg*8 + k0);
        #pragma unroll
        for (int mt=0; mt<4; mt++)
          acc[mt][t4] = __builtin_amdgcn_mfma_f32_16x16x32_bf16(a[mt], b, acc[mt][t4], 0, 0, 0);
      }
    }
  }

  // epilogue: score partials (ta includes ba1) + H writes (nt==13, e=208)
  float sacc[4][4];
  #pragma unroll
  for (int mt=0; mt<4; mt++)
    #pragma unroll
    for (int i=0; i<4; i++) sacc[mt][i] = 0.f;
  #pragma unroll
  for (int t4=0; t4<4; t4++){
    int nt = wave + t4*4;
    if (nt < 13){
      int e = nt*16 + lr;
      if (e < 200){
        float a2v = att2[e];
        #pragma unroll
        for (int mt=0; mt<4; mt++){
          #pragma unroll
          for (int i=0; i<4; i++){
            int p = p0 + mt*16 + lg*4 + i;
            float v = acc[mt][t4][i] + ta[(size_t)p*200 + e];
            sacc[mt][i] += fmaxf(v, 0.f) * a2v;
          }
        }
      }
    } else if (nt == 13 && lr == 0){
      #pragma unroll
      for (int mt=0; mt<4; mt++)
        #pragma unroll
        for (int i=0; i<4; i++)
          Hbuf[(size_t)(p0 + mt*16 + lg*4 + i)*NCH + c] = acc[mt][t4][i];
    }
  }
  __syncthreads();                       // s_h reads done; safe to alias
  float* s_red = reinterpret_cast<float*>(s_h);   // [4][64]
  #pragma unroll
  for (int mt=0; mt<4; mt++){
    #pragma unroll
    for (int i=0; i<4; i++){
      float s = sacc[mt][i];
      s += __shfl_xor(s, 1);
      s += __shfl_xor(s, 2);
      s += __shfl_xor(s, 4);
      s += __shfl_xor(s, 8);
      if (lr == 0) s_red[wave*64 + mt*16 + lg*4 + i] = s;
    }
  }
  __syncthreads();
  if (tid < 64){
    float r = s_red[tid] + s_red[64+tid] + s_red[128+tid] + s_red[192+tid];
    int p = p0 + tid;
    float w200 = att2[200], w201 = att2[201], b2 = ba2[0];
    float w0 = li[(size_t)p*240 + 84 + c];   // local_inputs[p,7,c]
    float w1 = li[(size_t)p*240 + 72 + c];   // local_inputs[p,6,c]
    score[(size_t)p*NCH + c] = fmaxf(r + w0*w200 + w1*w201 + b2, 0.f);
  }
}

// ---------- K3: fused softmax + output. block = t (64), thread = b (128)
__global__ __launch_bounds__(128) void k_sm_final(
    const float* __restrict__ score, const float* __restrict__ Hbuf,
    const float* __restrict__ Tbuf, const float* __restrict__ kconst,
    const float* __restrict__ labels, float* __restrict__ out)
{
  int t = blockIdx.x;
  int b = threadIdx.x;
  __shared__ float ws_f[NCH*NB];    // within-t wsoft, flat [c*128 + b]
  int p = b*NTT + t;
  const float* s = score + (size_t)p*NCH;
  float v[NCH];
  float m = -1e30f;
  #pragma unroll
  for (int c=0; c<NCH; c++){ v[c] = s[c]; m = fmaxf(m, v[c]); }
  float sum = 0.f;
  #pragma unroll
  for (int c=0; c<NCH; c++){ v[c] = __expf(v[c]-m); sum += v[c]; }
  float inv = __builtin_amdgcn_rcpf(sum);
  #pragma unroll
  for (int c=0; c<NCH; c++)
    ws_f[c*NB + b] = v[c]*inv;
  __syncthreads();
  // reference reshape scramble: w[p, c] = ws_f[b*12 + c]
  float acc = Tbuf[p] + kconst[0];
  const float* Hp = Hbuf + (size_t)p*NCH;
  int base = b*NCH;
  #pragma unroll
  for (int c=0; c<NCH; c++)
    acc += ws_f[base + c] * Hp[c];
  out[(size_t)t*NB + b] = acc;
  out[NP + (size_t)t*NB + b] = labels[p];
}

extern "C" void kernel_launch(void* const* d_in, const int* in_sizes, int n_in,
                              void* d_out, int out_size, void* d_ws, size_t ws_size,
                              hipStream_t stream)
{
  const float* li     = (const float*)d_in[0];
  const float* labels = (const float*)d_in[1];
  const float* extras = (const float*)d_in[2];
  const float* Wih    = (const float*)d_in[5];
  const float* bih    = (const float*)d_in[6];
  const float* bhh    = (const float*)d_in[7];
  const float* Wt     = (const float*)d_in[8];
  const float* bti    = (const float*)d_in[9];
  const float* bth    = (const float*)d_in[10];
  const float* Att1   = (const float*)d_in[11];
  const float* ba1    = (const float*)d_in[12];
  const float* Att2   = (const float*)d_in[13];
  const float* ba2    = (const float*)d_in[14];
  const float* fuse2  = (const float*)d_in[15];
  const float* bf2    = (const float*)d_in[16];
  const float* Wout   = (const float*)d_in[17];
  const float* bout   = (const float*)d_in[18];
  float* out = (float*)d_out;

  char* ws = (char*)d_ws;
  float* ta     = (float*)ws;                                       //  6,553,600
  float* score  = (float*)(ws + 6553600);                           //    393,216
  float* Hbuf   = (float*)(ws + 6946816);                           //    393,216
  float* Tbuf   = (float*)(ws + 7340032);                           //     32,768
  unsigned short* a1hi2 = (unsigned short*)(ws + 7372800);          //    143,360
  unsigned short* a1lo2 = (unsigned short*)(ws + 7516160);          //    143,360
  unsigned short* wg3   = (unsigned short*)(ws + 7659520);          //    184,320
  float* bsum3  = (float*)(ws + 7843840);                           //     46,080
  unsigned short* Sbf   = (unsigned short*)(ws + 7889920);          //  1,572,864
  float* kconst = (float*)(ws + 9462784);                           //          4

  k_prep<<<1990, 256, 0, stream>>>(Att1, ba1, Wih, bih, bhh, fuse2, bf2,
                                   Wout, bout, li,
                                   a1hi2, a1lo2, wg3, bsum3, Sbf, kconst);
  k_ht<<<NP/PB, 320, 0, stream>>>(extras, Wt, bti, bth, a1lo2, ta, Tbuf);
  k_hs<<<NCH*128, 256, 0, stream>>>(li, Sbf, wg3, bsum3, a1hi2, ta, Att2, ba2,
                                    Hbuf, score);
  k_sm_final<<<NTT, NB, 0, stream>>>(score, Hbuf, Tbuf, kconst, labels, out);
}